// Round 2
// baseline (469.766 us; speedup 1.0000x reference)
//
#include <hip/hip_runtime.h>
#include <hip/hip_bf16.h>

#define B_ 2
#define S_ 2048
#define D_ 768
#define H_ 12
#define DH_ 64
#define M_ (B_*S_)     // 4096
#define BH_ (B_*H_)    // 24

typedef __bf16 v8bf __attribute__((ext_vector_type(8)));
typedef __bf16 v4bf __attribute__((ext_vector_type(4)));
typedef float  v4f  __attribute__((ext_vector_type(4)));

static __device__ __forceinline__ v4f mfma16(v8bf a, v8bf b, v4f c) {
  return __builtin_amdgcn_mfma_f32_16x16x32_bf16(a, b, c, 0, 0, 0);
}

// ---------------- fp32 -> bf16 conversion ----------------
__global__ __launch_bounds__(256) void convert_kernel(
    const float* __restrict__ q, const float* __restrict__ k, const float* __restrict__ v,
    const float* __restrict__ Wq, const float* __restrict__ Wk,
    const float* __restrict__ Wv, const float* __restrict__ Wo,
    __bf16* __restrict__ Xq, __bf16* __restrict__ Xk, __bf16* __restrict__ Xv,
    __bf16* __restrict__ Wqb, __bf16* __restrict__ Wkb,
    __bf16* __restrict__ Wvb, __bf16* __restrict__ Wob)
{
  const float* src; __bf16* dst; int n;
  switch (blockIdx.y) {
    case 0: src = q;  dst = Xq;  n = M_*D_; break;
    case 1: src = k;  dst = Xk;  n = M_*D_; break;
    case 2: src = v;  dst = Xv;  n = M_*D_; break;
    case 3: src = Wq; dst = Wqb; n = D_*D_; break;
    case 4: src = Wk; dst = Wkb; n = D_*D_; break;
    case 5: src = Wv; dst = Wvb; n = D_*D_; break;
    default: src = Wo; dst = Wob; n = D_*D_; break;
  }
  int n4 = n >> 2;
  for (int i = blockIdx.x*blockDim.x + threadIdx.x; i < n4; i += gridDim.x*blockDim.x) {
    float4 x = ((const float4*)src)[i];
    v4bf y;
    y[0] = (__bf16)x.x; y[1] = (__bf16)x.y; y[2] = (__bf16)x.z; y[3] = (__bf16)x.w;
    ((v4bf*)dst)[i] = y;
  }
}

// ---------------- shared NT-GEMM core: C[128x128] = A @ W^T ----------------
static __device__ __forceinline__ void gemm_core(
    const __bf16* __restrict__ A, const __bf16* __restrict__ W,
    int m0, int n0, v4f acc[4][4])
{
  const int lane = threadIdx.x & 63;
  const int wave = threadIdx.x >> 6;
  const int wm = (wave >> 1) << 6;   // wave 64x64 sub-tile
  const int wn = (wave & 1) << 6;
  const int row  = lane & 15;
  const int koff = (lane >> 4) << 3;
  const __bf16* Ab = A + (size_t)(m0 + wm + row) * D_ + koff;
  const __bf16* Wb = W + (size_t)(n0 + wn + row) * D_ + koff;
  for (int k0 = 0; k0 < D_; k0 += 32) {
    v8bf a[4], b[4];
    #pragma unroll
    for (int i = 0; i < 4; i++) a[i] = *(const v8bf*)(Ab + (size_t)(16*i)*D_ + k0);
    #pragma unroll
    for (int j = 0; j < 4; j++) b[j] = *(const v8bf*)(Wb + (size_t)(16*j)*D_ + k0);
    #pragma unroll
    for (int i = 0; i < 4; i++)
      #pragma unroll
      for (int j = 0; j < 4; j++)
        acc[i][j] = mfma16(a[i], b[j], acc[i][j]);
  }
}

// ---------------- QKV projection: write qh/kh [B,H,S,DH], vt [B,H,DH,S] ----------------
__global__ __launch_bounds__(256) void qkv_gemm(
    const __bf16* __restrict__ Xq, const __bf16* __restrict__ Xk, const __bf16* __restrict__ Xv,
    const __bf16* __restrict__ Wqb, const __bf16* __restrict__ Wkb, const __bf16* __restrict__ Wvb,
    const float* __restrict__ bq, const float* __restrict__ bk, const float* __restrict__ bv,
    __bf16* __restrict__ qh, __bf16* __restrict__ kh, __bf16* __restrict__ vt)
{
  const int mode = blockIdx.z;
  const __bf16* A = (mode == 0) ? Xq : (mode == 1) ? Xk : Xv;
  const __bf16* W = (mode == 0) ? Wqb : (mode == 1) ? Wkb : Wvb;
  const float* bias = (mode == 0) ? bq : (mode == 1) ? bk : bv;
  const int m0 = blockIdx.y << 7, n0 = blockIdx.x << 7;
  v4f acc[4][4];
  #pragma unroll
  for (int i = 0; i < 4; i++)
    #pragma unroll
    for (int j = 0; j < 4; j++) { v4f z = {0.f,0.f,0.f,0.f}; acc[i][j] = z; }
  gemm_core(A, W, m0, n0, acc);

  const int lane = threadIdx.x & 63;
  const int wave = threadIdx.x >> 6;
  const int wm = (wave >> 1) << 6, wn = (wave & 1) << 6;
  const int col = lane & 15, quad = lane >> 4;
  float bb[4]; int nn[4];
  #pragma unroll
  for (int j = 0; j < 4; j++) { nn[j] = n0 + wn + 16*j + col; bb[j] = bias[nn[j]]; }

  if (mode < 2) {
    __bf16* dst = (mode == 0) ? qh : kh;
    #pragma unroll
    for (int i = 0; i < 4; i++)
      #pragma unroll
      for (int r = 0; r < 4; r++) {
        int m = m0 + wm + 16*i + quad*4 + r;
        int batch = m >> 11, s = m & (S_-1);
        #pragma unroll
        for (int j = 0; j < 4; j++) {
          int n = nn[j];
          dst[(((size_t)batch*H_ + (n >> 6))*S_ + s)*DH_ + (n & 63)] =
              (__bf16)(acc[i][j][r] + bb[j]);
        }
      }
  } else {
    // V: transposed store -> vt[b][h][d][s], pack 4 consecutive s per lane
    #pragma unroll
    for (int i = 0; i < 4; i++) {
      int mbase = m0 + wm + 16*i + quad*4;
      int batch = mbase >> 11, s0 = mbase & (S_-1);
      #pragma unroll
      for (int j = 0; j < 4; j++) {
        int n = nn[j];
        v4bf pk;
        #pragma unroll
        for (int r = 0; r < 4; r++) pk[r] = (__bf16)(acc[i][j][r] + bb[j]);
        *(v4bf*)(vt + (((size_t)batch*H_ + (n >> 6))*DH_ + (n & 63))*S_ + s0) = pk;
      }
    }
  }
}

// ---------------- flash attention: one wave = 16 queries, 128-key tiles ----------------
// LDS P-tile is wave-private: written and read only by the owning wave, so no
// __syncthreads needed (compiler's lgkmcnt ordering covers same-wave LDS dep).
__global__ __launch_bounds__(256) void attn_kernel(
    const __bf16* __restrict__ qh, const __bf16* __restrict__ kh, const __bf16* __restrict__ vt,
    const float* __restrict__ mask, __bf16* __restrict__ ao)
{
  __shared__ __bf16 plds[4][16][136];   // per-wave 16x128 P tile, +8 elem pad (16B-aligned rows)
  const int bh = blockIdx.y;
  const int wave = threadIdx.x >> 6, lane = threadIdx.x & 63;
  const int col = lane & 15, quad = lane >> 4, koff = quad << 3;
  const int q0 = (blockIdx.x << 6) + (wave << 4);
  const int batch = bh / H_, h = bh % H_;
  const __bf16* qb = qh + (size_t)bh * S_ * DH_;
  const __bf16* kb = kh + (size_t)bh * S_ * DH_;
  const __bf16* vb = vt + (size_t)bh * DH_ * S_;
  __bf16 (*pt)[136] = plds[wave];

  v8bf Aq0 = *(const v8bf*)(qb + (size_t)(q0 + col)*DH_ + koff);
  v8bf Aq1 = *(const v8bf*)(qb + (size_t)(q0 + col)*DH_ + 32 + koff);
  v4f O[4];
  #pragma unroll
  for (int f = 0; f < 4; f++) { v4f z = {0.f,0.f,0.f,0.f}; O[f] = z; }
  float mi[4], li[4];
  #pragma unroll
  for (int r = 0; r < 4; r++) { mi[r] = -1e30f; li[r] = 0.f; }
  const float C1 = 0.18033688011112042f;  // log2(e)/sqrt(DH)

  for (int kt = 0; kt < S_; kt += 128) {
    // ---- QK^T: 16x128 scores in 8 v4f accumulators ----
    v4f sc[8];
    #pragma unroll
    for (int j = 0; j < 8; j++) {
      const __bf16* kr = kb + (size_t)(kt + 16*j + col)*DH_;
      v8bf b0 = *(const v8bf*)(kr + koff);
      v8bf b1 = *(const v8bf*)(kr + 32 + koff);
      v4f z = {0.f,0.f,0.f,0.f};
      z = mfma16(Aq0, b0, z);
      sc[j] = mfma16(Aq1, b1, z);
    }
    // ---- online softmax over the 128-key tile (amortized reductions) ----
    #pragma unroll
    for (int r = 0; r < 4; r++) {
      const int srow = q0 + quad*4 + r;
      const float* mrow = mask + (size_t)srow*S_ + kt + col;
      float x[8]; float xm = -1e30f;
      #pragma unroll
      for (int j = 0; j < 8; j++) {
        x[j] = (sc[j][r] + mrow[16*j]) * C1;
        xm = fmaxf(xm, x[j]);
      }
      xm = fmaxf(xm, __shfl_xor(xm, 1));
      xm = fmaxf(xm, __shfl_xor(xm, 2));
      xm = fmaxf(xm, __shfl_xor(xm, 4));
      xm = fmaxf(xm, __shfl_xor(xm, 8));
      float mn = fmaxf(mi[r], xm);
      float alpha = exp2f(mi[r] - mn);
      mi[r] = mn;
      float rs = 0.f;
      #pragma unroll
      for (int j = 0; j < 8; j++) {
        float p = exp2f(x[j] - mn);
        rs += p;
        pt[quad*4 + r][16*j + col] = (__bf16)p;
      }
      rs += __shfl_xor(rs, 1);
      rs += __shfl_xor(rs, 2);
      rs += __shfl_xor(rs, 4);
      rs += __shfl_xor(rs, 8);
      li[r] = li[r]*alpha + rs;
      #pragma unroll
      for (int f = 0; f < 4; f++) O[f][r] *= alpha;
    }
    // ---- PV: O(16x64) += P(16x128) @ V^T(128x64) ----
    #pragma unroll
    for (int st = 0; st < 4; st++) {
      v8bf Ap = *(const v8bf*)(&pt[col][st*32 + koff]);
      #pragma unroll
      for (int f = 0; f < 4; f++) {
        v8bf Bv = *(const v8bf*)(vb + (size_t)(f*16 + col)*S_ + kt + st*32 + koff);
        O[f] = mfma16(Ap, Bv, O[f]);
      }
    }
  }

  float inv[4];
  #pragma unroll
  for (int r = 0; r < 4; r++) inv[r] = 1.f / li[r];
  #pragma unroll
  for (int f = 0; f < 4; f++)
    #pragma unroll
    for (int r = 0; r < 4; r++) {
      int s = q0 + quad*4 + r;
      ao[((size_t)batch*S_ + s)*D_ + h*DH_ + f*16 + col] = (__bf16)(O[f][r] * inv[r]);
    }
}

// ---------------- output projection: fp32 out ----------------
__global__ __launch_bounds__(256) void out_gemm(
    const __bf16* __restrict__ Ao, const __bf16* __restrict__ Wob,
    const float* __restrict__ bo, float* __restrict__ out)
{
  const int m0 = blockIdx.y << 7, n0 = blockIdx.x << 7;
  v4f acc[4][4];
  #pragma unroll
  for (int i = 0; i < 4; i++)
    #pragma unroll
    for (int j = 0; j < 4; j++) { v4f z = {0.f,0.f,0.f,0.f}; acc[i][j] = z; }
  gemm_core(Ao, Wob, m0, n0, acc);

  const int lane = threadIdx.x & 63;
  const int wave = threadIdx.x >> 6;
  const int wm = (wave >> 1) << 6, wn = (wave & 1) << 6;
  const int col = lane & 15, quad = lane >> 4;
  float bb[4]; int nn[4];
  #pragma unroll
  for (int j = 0; j < 4; j++) { nn[j] = n0 + wn + 16*j + col; bb[j] = bo[nn[j]]; }
  #pragma unroll
  for (int i = 0; i < 4; i++)
    #pragma unroll
    for (int r = 0; r < 4; r++) {
      int m = m0 + wm + 16*i + quad*4 + r;
      #pragma unroll
      for (int j = 0; j < 4; j++)
        out[(size_t)m*D_ + nn[j]] = acc[i][j][r] + bb[j];
    }
}

extern "C" void kernel_launch(void* const* d_in, const int* in_sizes, int n_in,
                              void* d_out, int out_size, void* d_ws, size_t ws_size,
                              hipStream_t stream)
{
  const float* q    = (const float*)d_in[0];
  const float* k    = (const float*)d_in[1];
  const float* v    = (const float*)d_in[2];
  const float* mask = (const float*)d_in[3];
  const float* Wq   = (const float*)d_in[4];
  const float* bq   = (const float*)d_in[5];
  const float* Wk   = (const float*)d_in[6];
  const float* bk   = (const float*)d_in[7];
  const float* Wv   = (const float*)d_in[8];
  const float* bv   = (const float*)d_in[9];
  const float* Wo   = (const float*)d_in[10];
  const float* bo   = (const float*)d_in[11];

  const size_t XN = (size_t)M_ * D_;
  const size_t WN = (size_t)D_ * D_;
  const size_t HN = (size_t)BH_ * S_ * DH_;

  char* ws = (char*)d_ws;
  __bf16* Xq  = (__bf16*)ws;                 ws += XN * 2;
  __bf16* Xk  = (__bf16*)ws;                 ws += XN * 2;
  __bf16* Xv  = (__bf16*)ws;                 ws += XN * 2;
  __bf16* Wqb = (__bf16*)ws;                 ws += WN * 2;
  __bf16* Wkb = (__bf16*)ws;                 ws += WN * 2;
  __bf16* Wvb = (__bf16*)ws;                 ws += WN * 2;
  __bf16* Wob = (__bf16*)ws;                 ws += WN * 2;
  __bf16* qhb = (__bf16*)ws;                 ws += HN * 2;
  __bf16* khb = (__bf16*)ws;                 ws += HN * 2;
  __bf16* vtb = (__bf16*)ws;                 ws += HN * 2;
  __bf16* aob = (__bf16*)ws;                 ws += XN * 2;

  convert_kernel<<<dim3(3072, 7), 256, 0, stream>>>(
      q, k, v, Wq, Wk, Wv, Wo, Xq, Xk, Xv, Wqb, Wkb, Wvb, Wob);
  qkv_gemm<<<dim3(6, 32, 3), 256, 0, stream>>>(
      Xq, Xk, Xv, Wqb, Wkb, Wvb, bq, bk, bv, qhb, khb, vtb);
  attn_kernel<<<dim3(32, 24), 256, 0, stream>>>(qhb, khb, vtb, mask, aob);
  out_gemm<<<dim3(6, 32), 256, 0, stream>>>(aob, Wob, bo, (float*)d_out);
}

// Round 3
// 426.420 us; speedup vs baseline: 1.1017x; 1.1017x over previous
//
#include <hip/hip_runtime.h>
#include <hip/hip_bf16.h>

#define B_ 2
#define S_ 2048
#define D_ 768
#define H_ 12
#define DH_ 64
#define M_ (B_*S_)     // 4096
#define BH_ (B_*H_)    // 24

typedef __bf16 v8bf __attribute__((ext_vector_type(8)));
typedef __bf16 v4bf __attribute__((ext_vector_type(4)));
typedef float  v4f  __attribute__((ext_vector_type(4)));

static __device__ __forceinline__ v4f mfma16(v8bf a, v8bf b, v4f c) {
  return __builtin_amdgcn_mfma_f32_16x16x32_bf16(a, b, c, 0, 0, 0);
}

// ---------------- fp32 -> bf16 conversion ----------------
__global__ __launch_bounds__(256) void convert_kernel(
    const float* __restrict__ q, const float* __restrict__ k, const float* __restrict__ v,
    const float* __restrict__ Wq, const float* __restrict__ Wk,
    const float* __restrict__ Wv, const float* __restrict__ Wo,
    __bf16* __restrict__ Xq, __bf16* __restrict__ Xk, __bf16* __restrict__ Xv,
    __bf16* __restrict__ Wqb, __bf16* __restrict__ Wkb,
    __bf16* __restrict__ Wvb, __bf16* __restrict__ Wob)
{
  const float* src; __bf16* dst; int n;
  switch (blockIdx.y) {
    case 0: src = q;  dst = Xq;  n = M_*D_; break;
    case 1: src = k;  dst = Xk;  n = M_*D_; break;
    case 2: src = v;  dst = Xv;  n = M_*D_; break;
    case 3: src = Wq; dst = Wqb; n = D_*D_; break;
    case 4: src = Wk; dst = Wkb; n = D_*D_; break;
    case 5: src = Wv; dst = Wvb; n = D_*D_; break;
    default: src = Wo; dst = Wob; n = D_*D_; break;
  }
  int n4 = n >> 2;
  for (int i = blockIdx.x*blockDim.x + threadIdx.x; i < n4; i += gridDim.x*blockDim.x) {
    float4 x = ((const float4*)src)[i];
    v4bf y;
    y[0] = (__bf16)x.x; y[1] = (__bf16)x.y; y[2] = (__bf16)x.z; y[3] = (__bf16)x.w;
    ((v4bf*)dst)[i] = y;
  }
}

// ---------------- shared NT-GEMM core: C[128x128] = A @ W^T ----------------
static __device__ __forceinline__ void gemm_core(
    const __bf16* __restrict__ A, const __bf16* __restrict__ W,
    int m0, int n0, v4f acc[4][4])
{
  const int lane = threadIdx.x & 63;
  const int wave = threadIdx.x >> 6;
  const int wm = (wave >> 1) << 6;   // wave 64x64 sub-tile
  const int wn = (wave & 1) << 6;
  const int row  = lane & 15;
  const int koff = (lane >> 4) << 3;
  const __bf16* Ab = A + (size_t)(m0 + wm + row) * D_ + koff;
  const __bf16* Wb = W + (size_t)(n0 + wn + row) * D_ + koff;
  for (int k0 = 0; k0 < D_; k0 += 32) {
    v8bf a[4], b[4];
    #pragma unroll
    for (int i = 0; i < 4; i++) a[i] = *(const v8bf*)(Ab + (size_t)(16*i)*D_ + k0);
    #pragma unroll
    for (int j = 0; j < 4; j++) b[j] = *(const v8bf*)(Wb + (size_t)(16*j)*D_ + k0);
    #pragma unroll
    for (int i = 0; i < 4; i++)
      #pragma unroll
      for (int j = 0; j < 4; j++)
        acc[i][j] = mfma16(a[i], b[j], acc[i][j]);
  }
}

// ---------------- QKV projection: write qh/kh [B,H,S,DH], vt [B,H,DH,S] ----------------
__global__ __launch_bounds__(256) void qkv_gemm(
    const __bf16* __restrict__ Xq, const __bf16* __restrict__ Xk, const __bf16* __restrict__ Xv,
    const __bf16* __restrict__ Wqb, const __bf16* __restrict__ Wkb, const __bf16* __restrict__ Wvb,
    const float* __restrict__ bq, const float* __restrict__ bk, const float* __restrict__ bv,
    __bf16* __restrict__ qh, __bf16* __restrict__ kh, __bf16* __restrict__ vt)
{
  const int mode = blockIdx.z;
  const __bf16* A = (mode == 0) ? Xq : (mode == 1) ? Xk : Xv;
  const __bf16* W = (mode == 0) ? Wqb : (mode == 1) ? Wkb : Wvb;
  const float* bias = (mode == 0) ? bq : (mode == 1) ? bk : bv;
  const int m0 = blockIdx.y << 7, n0 = blockIdx.x << 7;
  v4f acc[4][4];
  #pragma unroll
  for (int i = 0; i < 4; i++)
    #pragma unroll
    for (int j = 0; j < 4; j++) { v4f z = {0.f,0.f,0.f,0.f}; acc[i][j] = z; }
  gemm_core(A, W, m0, n0, acc);

  const int lane = threadIdx.x & 63;
  const int wave = threadIdx.x >> 6;
  const int wm = (wave >> 1) << 6, wn = (wave & 1) << 6;
  const int col = lane & 15, quad = lane >> 4;
  float bb[4]; int nn[4];
  #pragma unroll
  for (int j = 0; j < 4; j++) { nn[j] = n0 + wn + 16*j + col; bb[j] = bias[nn[j]]; }

  if (mode < 2) {
    __bf16* dst = (mode == 0) ? qh : kh;
    #pragma unroll
    for (int i = 0; i < 4; i++)
      #pragma unroll
      for (int r = 0; r < 4; r++) {
        int m = m0 + wm + 16*i + quad*4 + r;
        int batch = m >> 11, s = m & (S_-1);
        #pragma unroll
        for (int j = 0; j < 4; j++) {
          int n = nn[j];
          dst[(((size_t)batch*H_ + (n >> 6))*S_ + s)*DH_ + (n & 63)] =
              (__bf16)(acc[i][j][r] + bb[j]);
        }
      }
  } else {
    // V: transposed store -> vt[b][h][d][s], pack 4 consecutive s per lane
    #pragma unroll
    for (int i = 0; i < 4; i++) {
      int mbase = m0 + wm + 16*i + quad*4;
      int batch = mbase >> 11, s0 = mbase & (S_-1);
      #pragma unroll
      for (int j = 0; j < 4; j++) {
        int n = nn[j];
        v4bf pk;
        #pragma unroll
        for (int r = 0; r < 4; r++) pk[r] = (__bf16)(acc[i][j][r] + bb[j]);
        *(v4bf*)(vt + (((size_t)batch*H_ + (n >> 6))*DH_ + (n & 63))*S_ + s0) = pk;
      }
    }
  }
}

// ---------------- flash attention, transposed scores ----------------
// One wave = 16 queries, 32-key tiles (round-1 memory pattern).
// St = K·Q^T so C-layout gives: col(lane&15) = QUERY, quad*4+r = KEY.
// Softmax reduction over keys = 7 in-register ops + 2 shuffles (xor16/32).
// PV as O^T = V^T·P^T; output O^T has col=query, rows=d -> v4bf stores.
__global__ __launch_bounds__(256) void attn_kernel(
    const __bf16* __restrict__ qh, const __bf16* __restrict__ kh, const __bf16* __restrict__ vt,
    const float* __restrict__ mask, __bf16* __restrict__ ao)
{
  __shared__ __bf16 plds[4][16][40];   // P[q][key] per wave, padded rows
  const int bh = blockIdx.y;
  const int wave = threadIdx.x >> 6, lane = threadIdx.x & 63;
  const int col = lane & 15, quad = lane >> 4, koff = quad << 3;
  const int q0 = (blockIdx.x << 6) + (wave << 4);
  const int batch = bh / H_, h = bh % H_;
  const __bf16* qb = qh + (size_t)bh * S_ * DH_;
  const __bf16* kb = kh + (size_t)bh * S_ * DH_;
  const __bf16* vb = vt + (size_t)bh * DH_ * S_;
  __bf16 (*pt)[40] = plds[wave];

  // Q fragments (B-operand of St MFMA): B[k][n=q] = Q[q0+col][k]
  v8bf Qf0 = *(const v8bf*)(qb + (size_t)(q0 + col)*DH_ + koff);
  v8bf Qf1 = *(const v8bf*)(qb + (size_t)(q0 + col)*DH_ + 32 + koff);

  v4f O[4];   // O^T tiles: O[f][r] = O^T[d=f*16+quad*4+r][q=col]
  #pragma unroll
  for (int f = 0; f < 4; f++) { v4f z = {0.f,0.f,0.f,0.f}; O[f] = z; }
  float mi = -3e38f, li = 0.f;   // per-lane state for query q0+col (replicated across quads)
  const float C1 = 0.18033688011112042f;  // log2(e)/sqrt(DH)
  const float* mrow = mask + (size_t)(q0 + col)*S_ + quad*4;

  for (int kt = 0; kt < S_; kt += 32) {
    // ---- St = K·Q^T: A[m=key][k=d] from kh, B = Qf ----
    const __bf16* kr0 = kb + (size_t)(kt + col)*DH_;
    const __bf16* kr1 = kb + (size_t)(kt + 16 + col)*DH_;
    v8bf Kf00 = *(const v8bf*)(kr0 + koff);
    v8bf Kf01 = *(const v8bf*)(kr0 + 32 + koff);
    v8bf Kf10 = *(const v8bf*)(kr1 + koff);
    v8bf Kf11 = *(const v8bf*)(kr1 + 32 + koff);
    v4f s0 = {0.f,0.f,0.f,0.f}, s1 = {0.f,0.f,0.f,0.f};
    s0 = mfma16(Kf00, Qf0, s0); s0 = mfma16(Kf01, Qf1, s0);  // keys kt+quad*4+r
    s1 = mfma16(Kf10, Qf0, s1); s1 = mfma16(Kf11, Qf1, s1);  // keys kt+16+quad*4+r

    // ---- mask add + online softmax (keys live in regs + quads) ----
    float4 mk0 = *(const float4*)(mrow + kt);
    float4 mk1 = *(const float4*)(mrow + kt + 16);
    float x[8];
    x[0] = (s0[0] + mk0.x) * C1; x[1] = (s0[1] + mk0.y) * C1;
    x[2] = (s0[2] + mk0.z) * C1; x[3] = (s0[3] + mk0.w) * C1;
    x[4] = (s1[0] + mk1.x) * C1; x[5] = (s1[1] + mk1.y) * C1;
    x[6] = (s1[2] + mk1.z) * C1; x[7] = (s1[3] + mk1.w) * C1;
    float xm = fmaxf(fmaxf(fmaxf(x[0],x[1]),fmaxf(x[2],x[3])),
                     fmaxf(fmaxf(x[4],x[5]),fmaxf(x[6],x[7])));
    xm = fmaxf(xm, __shfl_xor(xm, 16));
    xm = fmaxf(xm, __shfl_xor(xm, 32));
    float mn = fmaxf(mi, xm);
    float alpha = exp2f(mi - mn);
    mi = mn;
    float p[8], rs = 0.f;
    #pragma unroll
    for (int j = 0; j < 8; j++) { p[j] = exp2f(x[j] - mn); rs += p[j]; }
    rs += __shfl_xor(rs, 16);
    rs += __shfl_xor(rs, 32);
    li = li*alpha + rs;
    #pragma unroll
    for (int f = 0; f < 4; f++) O[f] *= alpha;

    // ---- P -> LDS as P[q][key] (wave-private) ----
    v4bf pk0, pk1;
    #pragma unroll
    for (int r = 0; r < 4; r++) { pk0[r] = (__bf16)p[r]; pk1[r] = (__bf16)p[4+r]; }
    *(v4bf*)(&pt[col][quad*4])      = pk0;
    *(v4bf*)(&pt[col][16 + quad*4]) = pk1;
    __syncthreads();   // lockstep: keeps waves sharing K/V L1 lines (round-1 regime)

    // ---- O^T += V^T·P^T: A[m=d][k=key] from vt, B[k=key][n=q] from LDS ----
    v8bf Pf = *(const v8bf*)(&pt[col][koff]);
    #pragma unroll
    for (int f = 0; f < 4; f++) {
      v8bf Vf = *(const v8bf*)(vb + (size_t)(f*16 + col)*S_ + kt + koff);
      O[f] = mfma16(Vf, Pf, O[f]);
    }
  }

  // ---- epilogue: per-lane query = q0+col, 4 consecutive d per frag ----
  float inv = 1.f / li;
  __bf16* orow = ao + ((size_t)batch*S_ + q0 + col)*D_ + h*DH_ + quad*4;
  #pragma unroll
  for (int f = 0; f < 4; f++) {
    v4bf o;
    #pragma unroll
    for (int r = 0; r < 4; r++) o[r] = (__bf16)(O[f][r] * inv);
    *(v4bf*)(orow + f*16) = o;
  }
}

// ---------------- output projection: fp32 out ----------------
__global__ __launch_bounds__(256) void out_gemm(
    const __bf16* __restrict__ Ao, const __bf16* __restrict__ Wob,
    const float* __restrict__ bo, float* __restrict__ out)
{
  const int m0 = blockIdx.y << 7, n0 = blockIdx.x << 7;
  v4f acc[4][4];
  #pragma unroll
  for (int i = 0; i < 4; i++)
    #pragma unroll
    for (int j = 0; j < 4; j++) { v4f z = {0.f,0.f,0.f,0.f}; acc[i][j] = z; }
  gemm_core(Ao, Wob, m0, n0, acc);

  const int lane = threadIdx.x & 63;
  const int wave = threadIdx.x >> 6;
  const int wm = (wave >> 1) << 6, wn = (wave & 1) << 6;
  const int col = lane & 15, quad = lane >> 4;
  float bb[4]; int nn[4];
  #pragma unroll
  for (int j = 0; j < 4; j++) { nn[j] = n0 + wn + 16*j + col; bb[j] = bo[nn[j]]; }
  #pragma unroll
  for (int i = 0; i < 4; i++)
    #pragma unroll
    for (int r = 0; r < 4; r++) {
      int m = m0 + wm + 16*i + quad*4 + r;
      #pragma unroll
      for (int j = 0; j < 4; j++)
        out[(size_t)m*D_ + nn[j]] = acc[i][j][r] + bb[j];
    }
}

extern "C" void kernel_launch(void* const* d_in, const int* in_sizes, int n_in,
                              void* d_out, int out_size, void* d_ws, size_t ws_size,
                              hipStream_t stream)
{
  const float* q    = (const float*)d_in[0];
  const float* k    = (const float*)d_in[1];
  const float* v    = (const float*)d_in[2];
  const float* mask = (const float*)d_in[3];
  const float* Wq   = (const float*)d_in[4];
  const float* bq   = (const float*)d_in[5];
  const float* Wk   = (const float*)d_in[6];
  const float* bk   = (const float*)d_in[7];
  const float* Wv   = (const float*)d_in[8];
  const float* bv   = (const float*)d_in[9];
  const float* Wo   = (const float*)d_in[10];
  const float* bo   = (const float*)d_in[11];

  const size_t XN = (size_t)M_ * D_;
  const size_t WN = (size_t)D_ * D_;
  const size_t HN = (size_t)BH_ * S_ * DH_;

  char* ws = (char*)d_ws;
  __bf16* Xq  = (__bf16*)ws;                 ws += XN * 2;
  __bf16* Xk  = (__bf16*)ws;                 ws += XN * 2;
  __bf16* Xv  = (__bf16*)ws;                 ws += XN * 2;
  __bf16* Wqb = (__bf16*)ws;                 ws += WN * 2;
  __bf16* Wkb = (__bf16*)ws;                 ws += WN * 2;
  __bf16* Wvb = (__bf16*)ws;                 ws += WN * 2;
  __bf16* Wob = (__bf16*)ws;                 ws += WN * 2;
  __bf16* qhb = (__bf16*)ws;                 ws += HN * 2;
  __bf16* khb = (__bf16*)ws;                 ws += HN * 2;
  __bf16* vtb = (__bf16*)ws;                 ws += HN * 2;
  __bf16* aob = (__bf16*)ws;                 ws += XN * 2;

  convert_kernel<<<dim3(3072, 7), 256, 0, stream>>>(
      q, k, v, Wq, Wk, Wv, Wo, Xq, Xk, Xv, Wqb, Wkb, Wvb, Wob);
  qkv_gemm<<<dim3(6, 32, 3), 256, 0, stream>>>(
      Xq, Xk, Xv, Wqb, Wkb, Wvb, bq, bk, bv, qhb, khb, vtb);
  attn_kernel<<<dim3(32, 24), 256, 0, stream>>>(qhb, khb, vtb, mask, aob);
  out_gemm<<<dim3(6, 32), 256, 0, stream>>>(aob, Wob, bo, (float*)d_out);
}

// Round 4
// 348.027 us; speedup vs baseline: 1.3498x; 1.2252x over previous
//
#include <hip/hip_runtime.h>
#include <hip/hip_bf16.h>

#define B_ 2
#define S_ 2048
#define D_ 768
#define H_ 12
#define DH_ 64
#define M_ (B_*S_)     // 4096
#define BH_ (B_*H_)    // 24

typedef __bf16 v8bf __attribute__((ext_vector_type(8)));
typedef __bf16 v4bf __attribute__((ext_vector_type(4)));
typedef float  v4f  __attribute__((ext_vector_type(4)));

static __device__ __forceinline__ v4f mfma16(v8bf a, v8bf b, v4f c) {
  return __builtin_amdgcn_mfma_f32_16x16x32_bf16(a, b, c, 0, 0, 0);
}

// ---------------- fp32 -> bf16 conversion ----------------
__global__ __launch_bounds__(256) void convert_kernel(
    const float* __restrict__ q, const float* __restrict__ k, const float* __restrict__ v,
    const float* __restrict__ Wq, const float* __restrict__ Wk,
    const float* __restrict__ Wv, const float* __restrict__ Wo,
    __bf16* __restrict__ Xq, __bf16* __restrict__ Xk, __bf16* __restrict__ Xv,
    __bf16* __restrict__ Wqb, __bf16* __restrict__ Wkb,
    __bf16* __restrict__ Wvb, __bf16* __restrict__ Wob)
{
  const float* src; __bf16* dst; int n;
  switch (blockIdx.y) {
    case 0: src = q;  dst = Xq;  n = M_*D_; break;
    case 1: src = k;  dst = Xk;  n = M_*D_; break;
    case 2: src = v;  dst = Xv;  n = M_*D_; break;
    case 3: src = Wq; dst = Wqb; n = D_*D_; break;
    case 4: src = Wk; dst = Wkb; n = D_*D_; break;
    case 5: src = Wv; dst = Wvb; n = D_*D_; break;
    default: src = Wo; dst = Wob; n = D_*D_; break;
  }
  int n4 = n >> 2;
  for (int i = blockIdx.x*blockDim.x + threadIdx.x; i < n4; i += gridDim.x*blockDim.x) {
    float4 x = ((const float4*)src)[i];
    v4bf y;
    y[0] = (__bf16)x.x; y[1] = (__bf16)x.y; y[2] = (__bf16)x.z; y[3] = (__bf16)x.w;
    ((v4bf*)dst)[i] = y;
  }
}

// ---------------- shared NT-GEMM core: C[128x128] = A @ W^T ----------------
static __device__ __forceinline__ void gemm_core(
    const __bf16* __restrict__ A, const __bf16* __restrict__ W,
    int m0, int n0, v4f acc[4][4])
{
  const int lane = threadIdx.x & 63;
  const int wave = threadIdx.x >> 6;
  const int wm = (wave >> 1) << 6;   // wave 64x64 sub-tile
  const int wn = (wave & 1) << 6;
  const int row  = lane & 15;
  const int koff = (lane >> 4) << 3;
  const __bf16* Ab = A + (size_t)(m0 + wm + row) * D_ + koff;
  const __bf16* Wb = W + (size_t)(n0 + wn + row) * D_ + koff;
  for (int k0 = 0; k0 < D_; k0 += 32) {
    v8bf a[4], b[4];
    #pragma unroll
    for (int i = 0; i < 4; i++) a[i] = *(const v8bf*)(Ab + (size_t)(16*i)*D_ + k0);
    #pragma unroll
    for (int j = 0; j < 4; j++) b[j] = *(const v8bf*)(Wb + (size_t)(16*j)*D_ + k0);
    #pragma unroll
    for (int i = 0; i < 4; i++)
      #pragma unroll
      for (int j = 0; j < 4; j++)
        acc[i][j] = mfma16(a[i], b[j], acc[i][j]);
  }
}

// ---------------- QKV projection: write qh/kh [B,H,S,DH], vt [B,H,DH,S] ----------------
__global__ __launch_bounds__(256) void qkv_gemm(
    const __bf16* __restrict__ Xq, const __bf16* __restrict__ Xk, const __bf16* __restrict__ Xv,
    const __bf16* __restrict__ Wqb, const __bf16* __restrict__ Wkb, const __bf16* __restrict__ Wvb,
    const float* __restrict__ bq, const float* __restrict__ bk, const float* __restrict__ bv,
    __bf16* __restrict__ qh, __bf16* __restrict__ kh, __bf16* __restrict__ vt)
{
  const int mode = blockIdx.z;
  const __bf16* A = (mode == 0) ? Xq : (mode == 1) ? Xk : Xv;
  const __bf16* W = (mode == 0) ? Wqb : (mode == 1) ? Wkb : Wvb;
  const float* bias = (mode == 0) ? bq : (mode == 1) ? bk : bv;
  const int m0 = blockIdx.y << 7, n0 = blockIdx.x << 7;
  v4f acc[4][4];
  #pragma unroll
  for (int i = 0; i < 4; i++)
    #pragma unroll
    for (int j = 0; j < 4; j++) { v4f z = {0.f,0.f,0.f,0.f}; acc[i][j] = z; }
  gemm_core(A, W, m0, n0, acc);

  const int lane = threadIdx.x & 63;
  const int wave = threadIdx.x >> 6;
  const int wm = (wave >> 1) << 6, wn = (wave & 1) << 6;
  const int col = lane & 15, quad = lane >> 4;
  float bb[4]; int nn[4];
  #pragma unroll
  for (int j = 0; j < 4; j++) { nn[j] = n0 + wn + 16*j + col; bb[j] = bias[nn[j]]; }

  if (mode < 2) {
    __bf16* dst = (mode == 0) ? qh : kh;
    #pragma unroll
    for (int i = 0; i < 4; i++)
      #pragma unroll
      for (int r = 0; r < 4; r++) {
        int m = m0 + wm + 16*i + quad*4 + r;
        int batch = m >> 11, s = m & (S_-1);
        #pragma unroll
        for (int j = 0; j < 4; j++) {
          int n = nn[j];
          dst[(((size_t)batch*H_ + (n >> 6))*S_ + s)*DH_ + (n & 63)] =
              (__bf16)(acc[i][j][r] + bb[j]);
        }
      }
  } else {
    // V: transposed store -> vt[b][h][d][s], pack 4 consecutive s per lane
    #pragma unroll
    for (int i = 0; i < 4; i++) {
      int mbase = m0 + wm + 16*i + quad*4;
      int batch = mbase >> 11, s0 = mbase & (S_-1);
      #pragma unroll
      for (int j = 0; j < 4; j++) {
        int n = nn[j];
        v4bf pk;
        #pragma unroll
        for (int r = 0; r < 4; r++) pk[r] = (__bf16)(acc[i][j][r] + bb[j]);
        *(v4bf*)(vt + (((size_t)batch*H_ + (n >> 6))*DH_ + (n & 63))*S_ + s0) = pk;
      }
    }
  }
}

// ---------------- flash attention: 64 queries/block, split-K across 4 waves ----------------
// Block = 4 waves, all sharing one 64-query tile. Wave w owns keys [w*512,(w+1)*512),
// carrying 4 independent online-softmax chains (one per 16-query group) -> high ILP.
// Transposed scores St = K.Q^T (col=query, quad*4+r=key); mask folds into MFMA C-init.
// Partials (m, l, unnormalized O^T) combined in-block via LDS (flash-decoding style).
__global__ __launch_bounds__(256) void attn_kernel(
    const __bf16* __restrict__ qh, const __bf16* __restrict__ kh, const __bf16* __restrict__ vt,
    const float* __restrict__ mask, __bf16* __restrict__ ao)
{
  __shared__ __bf16 plds[4][4][16][40];  // [wave][qq][q within group][32 keys padded]
  __shared__ float mls[2][4][64];        // [m/l][wave][query]
  __shared__ float Ored[64][68];         // [query][d] fp32 combine buffer

  const int bh = blockIdx.y;
  const int wave = threadIdx.x >> 6, lane = threadIdx.x & 63;
  const int col = lane & 15, quad = lane >> 4, koff = quad << 3;
  const int q0 = blockIdx.x << 6;
  const int batch = bh / H_, h = bh % H_;
  const __bf16* qb = qh + (size_t)bh * S_ * DH_;
  const __bf16* kb = kh + (size_t)bh * S_ * DH_;
  const __bf16* vb = vt + (size_t)bh * DH_ * S_;
  __bf16 (*pt)[16][40] = plds[wave];

  // Q fragments for the 4 query groups (B-operand: B[k][n=q])
  v8bf Qf[4][2];
  #pragma unroll
  for (int qq = 0; qq < 4; qq++) {
    const __bf16* qr = qb + (size_t)(q0 + 16*qq + col)*DH_;
    Qf[qq][0] = *(const v8bf*)(qr + koff);
    Qf[qq][1] = *(const v8bf*)(qr + 32 + koff);
  }

  v4f O[4][4];   // [f: d=16f+quad*4+r][qq], unnormalized O^T
  #pragma unroll
  for (int f = 0; f < 4; f++)
    #pragma unroll
    for (int qq = 0; qq < 4; qq++) { v4f z = {0.f,0.f,0.f,0.f}; O[f][qq] = z; }
  float mi[4], li[4];
  #pragma unroll
  for (int qq = 0; qq < 4; qq++) { mi[qq] = -3e38f; li[qq] = 0.f; }
  const float C1 = 0.18033688011112042f;  // log2(e)/sqrt(DH)

  const int kbeg = wave << 9;             // this wave's 512-key chunk
  #pragma unroll 1
  for (int kt = kbeg; kt < kbeg + 512; kt += 32) {
    const __bf16* kr0 = kb + (size_t)(kt + col)*DH_;
    const __bf16* kr1 = kb + (size_t)(kt + 16 + col)*DH_;
    v8bf Kf00 = *(const v8bf*)(kr0 + koff);
    v8bf Kf01 = *(const v8bf*)(kr0 + 32 + koff);
    v8bf Kf10 = *(const v8bf*)(kr1 + koff);
    v8bf Kf11 = *(const v8bf*)(kr1 + 32 + koff);

    #pragma unroll
    for (int qq = 0; qq < 4; qq++) {
      const float* mrow = mask + (size_t)(q0 + 16*qq + col)*S_ + kt + quad*4;
      float4 mk0 = *(const float4*)(mrow);
      float4 mk1 = *(const float4*)(mrow + 16);
      v4f s0 = {mk0.x, mk0.y, mk0.z, mk0.w};   // mask as MFMA C-init
      v4f s1 = {mk1.x, mk1.y, mk1.z, mk1.w};
      s0 = mfma16(Kf00, Qf[qq][0], s0); s0 = mfma16(Kf01, Qf[qq][1], s0);
      s1 = mfma16(Kf10, Qf[qq][0], s1); s1 = mfma16(Kf11, Qf[qq][1], s1);

      float x[8];
      #pragma unroll
      for (int j = 0; j < 4; j++) { x[j] = s0[j]*C1; x[4+j] = s1[j]*C1; }
      float xm = fmaxf(fmaxf(fmaxf(x[0],x[1]),fmaxf(x[2],x[3])),
                       fmaxf(fmaxf(x[4],x[5]),fmaxf(x[6],x[7])));
      xm = fmaxf(xm, __shfl_xor(xm, 16));
      xm = fmaxf(xm, __shfl_xor(xm, 32));
      float mold = mi[qq];
      float mn = fmaxf(mold, xm);
      mi[qq] = mn;
      float p[8], rs = 0.f;
      #pragma unroll
      for (int j = 0; j < 8; j++) { p[j] = exp2f(x[j] - mn); rs += p[j]; }
      rs += __shfl_xor(rs, 16);
      rs += __shfl_xor(rs, 32);
      if (__any(xm > mold)) {           // rescale only when some lane got a new max
        float alpha = exp2f(mold - mn);
        li[qq] = li[qq]*alpha + rs;
        #pragma unroll
        for (int f = 0; f < 4; f++) O[f][qq] *= alpha;
      } else {
        li[qq] += rs;
      }
      v4bf pk0, pk1;
      #pragma unroll
      for (int r = 0; r < 4; r++) { pk0[r] = (__bf16)p[r]; pk1[r] = (__bf16)p[4+r]; }
      *(v4bf*)(&pt[qq][col][quad*4])      = pk0;
      *(v4bf*)(&pt[qq][col][16 + quad*4]) = pk1;
    }

    // PV: O^T += V^T · P^T   (wave-private LDS, no barrier needed)
    v8bf Pf[4];
    #pragma unroll
    for (int qq = 0; qq < 4; qq++) Pf[qq] = *(const v8bf*)(&pt[qq][col][koff]);
    #pragma unroll
    for (int f = 0; f < 4; f++) {
      v8bf Vf = *(const v8bf*)(vb + (size_t)(f*16 + col)*S_ + kt + koff);
      #pragma unroll
      for (int qq = 0; qq < 4; qq++)
        O[f][qq] = mfma16(Vf, Pf[qq], O[f][qq]);
    }
  }

  // ---- in-block split-K combine ----
  if (quad == 0) {
    #pragma unroll
    for (int qq = 0; qq < 4; qq++) {
      mls[0][wave][16*qq + col] = mi[qq];
      mls[1][wave][16*qq + col] = li[qq];
    }
  }
  __syncthreads();
  float wgt[4];
  #pragma unroll
  for (int qq = 0; qq < 4; qq++) {
    int q = 16*qq + col;
    float ms = fmaxf(fmaxf(mls[0][0][q], mls[0][1][q]),
                     fmaxf(mls[0][2][q], mls[0][3][q]));
    wgt[qq] = exp2f(mi[qq] - ms);
  }
  for (int w = 0; w < 4; w++) {
    if (wave == w) {
      #pragma unroll
      for (int qq = 0; qq < 4; qq++)
        #pragma unroll
        for (int f = 0; f < 4; f++) {
          float4* dst = (float4*)&Ored[16*qq + col][16*f + quad*4];
          float4 val;
          val.x = O[f][qq][0]*wgt[qq]; val.y = O[f][qq][1]*wgt[qq];
          val.z = O[f][qq][2]*wgt[qq]; val.w = O[f][qq][3]*wgt[qq];
          if (w != 0) {
            float4 old = *dst;
            val.x += old.x; val.y += old.y; val.z += old.z; val.w += old.w;
          }
          *dst = val;
        }
    }
    __syncthreads();
  }
  // ---- normalize + write: thread t -> query t>>2, 16 d's ----
  {
    int q = threadIdx.x >> 2, ds = (threadIdx.x & 3) << 4;
    float msq = fmaxf(fmaxf(mls[0][0][q], mls[0][1][q]),
                      fmaxf(mls[0][2][q], mls[0][3][q]));
    float lst = 0.f;
    #pragma unroll
    for (int w = 0; w < 4; w++) lst += mls[1][w][q] * exp2f(mls[0][w][q] - msq);
    float invl = 1.f / lst;
    __bf16* orow = ao + ((size_t)batch*S_ + q0 + q)*D_ + h*DH_ + ds;
    v8bf o0, o1;
    #pragma unroll
    for (int i = 0; i < 8; i++) {
      o0[i] = (__bf16)(Ored[q][ds + i] * invl);
      o1[i] = (__bf16)(Ored[q][ds + 8 + i] * invl);
    }
    *(v8bf*)orow = o0;
    *(v8bf*)(orow + 8) = o1;
  }
}

// ---------------- output projection: fp32 out ----------------
__global__ __launch_bounds__(256) void out_gemm(
    const __bf16* __restrict__ Ao, const __bf16* __restrict__ Wob,
    const float* __restrict__ bo, float* __restrict__ out)
{
  const int m0 = blockIdx.y << 7, n0 = blockIdx.x << 7;
  v4f acc[4][4];
  #pragma unroll
  for (int i = 0; i < 4; i++)
    #pragma unroll
    for (int j = 0; j < 4; j++) { v4f z = {0.f,0.f,0.f,0.f}; acc[i][j] = z; }
  gemm_core(Ao, Wob, m0, n0, acc);

  const int lane = threadIdx.x & 63;
  const int wave = threadIdx.x >> 6;
  const int wm = (wave >> 1) << 6, wn = (wave & 1) << 6;
  const int col = lane & 15, quad = lane >> 4;
  float bb[4]; int nn[4];
  #pragma unroll
  for (int j = 0; j < 4; j++) { nn[j] = n0 + wn + 16*j + col; bb[j] = bo[nn[j]]; }
  #pragma unroll
  for (int i = 0; i < 4; i++)
    #pragma unroll
    for (int r = 0; r < 4; r++) {
      int m = m0 + wm + 16*i + quad*4 + r;
      #pragma unroll
      for (int j = 0; j < 4; j++)
        out[(size_t)m*D_ + nn[j]] = acc[i][j][r] + bb[j];
    }
}

extern "C" void kernel_launch(void* const* d_in, const int* in_sizes, int n_in,
                              void* d_out, int out_size, void* d_ws, size_t ws_size,
                              hipStream_t stream)
{
  const float* q    = (const float*)d_in[0];
  const float* k    = (const float*)d_in[1];
  const float* v    = (const float*)d_in[2];
  const float* mask = (const float*)d_in[3];
  const float* Wq   = (const float*)d_in[4];
  const float* bq   = (const float*)d_in[5];
  const float* Wk   = (const float*)d_in[6];
  const float* bk   = (const float*)d_in[7];
  const float* Wv   = (const float*)d_in[8];
  const float* bv   = (const float*)d_in[9];
  const float* Wo   = (const float*)d_in[10];
  const float* bo   = (const float*)d_in[11];

  const size_t XN = (size_t)M_ * D_;
  const size_t WN = (size_t)D_ * D_;
  const size_t HN = (size_t)BH_ * S_ * DH_;

  char* ws = (char*)d_ws;
  __bf16* Xq  = (__bf16*)ws;                 ws += XN * 2;
  __bf16* Xk  = (__bf16*)ws;                 ws += XN * 2;
  __bf16* Xv  = (__bf16*)ws;                 ws += XN * 2;
  __bf16* Wqb = (__bf16*)ws;                 ws += WN * 2;
  __bf16* Wkb = (__bf16*)ws;                 ws += WN * 2;
  __bf16* Wvb = (__bf16*)ws;                 ws += WN * 2;
  __bf16* Wob = (__bf16*)ws;                 ws += WN * 2;
  __bf16* qhb = (__bf16*)ws;                 ws += HN * 2;
  __bf16* khb = (__bf16*)ws;                 ws += HN * 2;
  __bf16* vtb = (__bf16*)ws;                 ws += HN * 2;
  __bf16* aob = (__bf16*)ws;                 ws += XN * 2;

  convert_kernel<<<dim3(3072, 7), 256, 0, stream>>>(
      q, k, v, Wq, Wk, Wv, Wo, Xq, Xk, Xv, Wqb, Wkb, Wvb, Wob);
  qkv_gemm<<<dim3(6, 32, 3), 256, 0, stream>>>(
      Xq, Xk, Xv, Wqb, Wkb, Wvb, bq, bk, bv, qhb, khb, vtb);
  attn_kernel<<<dim3(32, 24), 256, 0, stream>>>(qhb, khb, vtb, mask, aob);
  out_gemm<<<dim3(6, 32), 256, 0, stream>>>(aob, Wob, bo, (float*)d_out);
}

// Round 5
// 313.240 us; speedup vs baseline: 1.4997x; 1.1111x over previous
//
#include <hip/hip_runtime.h>
#include <hip/hip_bf16.h>

#define B_ 2
#define S_ 2048
#define D_ 768
#define H_ 12
#define DH_ 64
#define M_ (B_*S_)     // 4096
#define BH_ (B_*H_)    // 24

typedef __bf16 v8bf __attribute__((ext_vector_type(8)));
typedef __bf16 v4bf __attribute__((ext_vector_type(4)));
typedef float  v4f  __attribute__((ext_vector_type(4)));

static __device__ __forceinline__ v4f mfma16(v8bf a, v8bf b, v4f c) {
  return __builtin_amdgcn_mfma_f32_16x16x32_bf16(a, b, c, 0, 0, 0);
}

// async global->LDS, 16 B/lane; dest = wave-uniform base + lane*16
static __device__ __forceinline__ void gload_lds16(const __bf16* g, __bf16* l) {
  __builtin_amdgcn_global_load_lds(
      (const __attribute__((address_space(1))) unsigned int*)g,
      (__attribute__((address_space(3))) unsigned int*)l,
      16, 0, 0);
}

// ---------------- fp32 -> bf16 conversion ----------------
__global__ __launch_bounds__(256) void convert_kernel(
    const float* __restrict__ q, const float* __restrict__ k, const float* __restrict__ v,
    const float* __restrict__ Wq, const float* __restrict__ Wk,
    const float* __restrict__ Wv, const float* __restrict__ Wo,
    __bf16* __restrict__ Xq, __bf16* __restrict__ Xk, __bf16* __restrict__ Xv,
    __bf16* __restrict__ Wqb, __bf16* __restrict__ Wkb,
    __bf16* __restrict__ Wvb, __bf16* __restrict__ Wob)
{
  const float* src; __bf16* dst; int n;
  switch (blockIdx.y) {
    case 0: src = q;  dst = Xq;  n = M_*D_; break;
    case 1: src = k;  dst = Xk;  n = M_*D_; break;
    case 2: src = v;  dst = Xv;  n = M_*D_; break;
    case 3: src = Wq; dst = Wqb; n = D_*D_; break;
    case 4: src = Wk; dst = Wkb; n = D_*D_; break;
    case 5: src = Wv; dst = Wvb; n = D_*D_; break;
    default: src = Wo; dst = Wob; n = D_*D_; break;
  }
  int n4 = n >> 2;
  for (int i = blockIdx.x*blockDim.x + threadIdx.x; i < n4; i += gridDim.x*blockDim.x) {
    float4 x = ((const float4*)src)[i];
    v4bf y;
    y[0] = (__bf16)x.x; y[1] = (__bf16)x.y; y[2] = (__bf16)x.z; y[3] = (__bf16)x.w;
    ((v4bf*)dst)[i] = y;
  }
}

// ---------------- m97-style LDS-staged NT-GEMM core: C[128x128] = A @ W^T ----------------
// LDS in FRAGMENT order: frag-block fb (16 rows x 32 k) = 1024 B at lA+fb*512 elems,
// lane L holds (row L&15, kchunk L>>4). DMA staging order == fragment order, so
// every MFMA fragment read is ds_read_b128 at fb*1024 + lane*16 (conflict-free).
static __device__ __forceinline__ void gemm_core_lds(
    const __bf16* __restrict__ A, const __bf16* __restrict__ W,
    int m0, int n0, __bf16* lA, __bf16* lB, v4f acc[4][4])
{
  const int lane = threadIdx.x & 63;
  const int wave = threadIdx.x >> 6;
  const int r16 = lane & 15;          // row within frag-block
  const int kc8 = (lane >> 4) << 3;   // k-chunk offset (0,8,16,24)
  const int fb0 = wave*2, fb1 = wave*2 + 1;   // frag-blocks this wave stages
  const __bf16* gA0 = A + (size_t)(m0 + fb0*16 + r16)*D_ + kc8;
  const __bf16* gA1 = A + (size_t)(m0 + fb1*16 + r16)*D_ + kc8;
  const __bf16* gB0 = W + (size_t)(n0 + fb0*16 + r16)*D_ + kc8;
  const __bf16* gB1 = W + (size_t)(n0 + fb1*16 + r16)*D_ + kc8;
  __bf16* lA0 = lA + fb0*512; __bf16* lA1 = lA + fb1*512;
  __bf16* lB0 = lB + fb0*512; __bf16* lB1 = lB + fb1*512;
  const int ia = (wave >> 1) << 2;    // A frag-block base for this wave's 64x64 subtile
  const int ib = (wave & 1) << 2;     // B frag-block base

  for (int k0 = 0; k0 < D_; k0 += 32) {
    gload_lds16(gA0 + k0, lA0);
    gload_lds16(gA1 + k0, lA1);
    gload_lds16(gB0 + k0, lB0);
    gload_lds16(gB1 + k0, lB1);
    __syncthreads();                  // drain vmcnt: staging complete
    v8bf a[4], b[4];
    #pragma unroll
    for (int i = 0; i < 4; i++) a[i] = *(const v8bf*)(lA + (ia+i)*512 + lane*8);
    #pragma unroll
    for (int j = 0; j < 4; j++) b[j] = *(const v8bf*)(lB + (ib+j)*512 + lane*8);
    #pragma unroll
    for (int i = 0; i < 4; i++)
      #pragma unroll
      for (int j = 0; j < 4; j++)
        acc[i][j] = mfma16(a[i], b[j], acc[i][j]);
    __syncthreads();                  // frags read; LDS reusable next iter
  }
}

// ---------------- QKV projection: write qh/kh [B,H,S,DH], vt [B,H,DH,S] ----------------
__global__ __launch_bounds__(256) void qkv_gemm(
    const __bf16* __restrict__ Xq, const __bf16* __restrict__ Xk, const __bf16* __restrict__ Xv,
    const __bf16* __restrict__ Wqb, const __bf16* __restrict__ Wkb, const __bf16* __restrict__ Wvb,
    const float* __restrict__ bq, const float* __restrict__ bk, const float* __restrict__ bv,
    __bf16* __restrict__ qh, __bf16* __restrict__ kh, __bf16* __restrict__ vt)
{
  __shared__ __bf16 lA[4096], lB[4096];
  const int mode = blockIdx.z;
  const __bf16* A = (mode == 0) ? Xq : (mode == 1) ? Xk : Xv;
  const __bf16* W = (mode == 0) ? Wqb : (mode == 1) ? Wkb : Wvb;
  const float* bias = (mode == 0) ? bq : (mode == 1) ? bk : bv;
  const int m0 = blockIdx.y << 7, n0 = blockIdx.x << 7;
  v4f acc[4][4];
  #pragma unroll
  for (int i = 0; i < 4; i++)
    #pragma unroll
    for (int j = 0; j < 4; j++) { v4f z = {0.f,0.f,0.f,0.f}; acc[i][j] = z; }
  gemm_core_lds(A, W, m0, n0, lA, lB, acc);

  const int lane = threadIdx.x & 63;
  const int wave = threadIdx.x >> 6;
  const int wm = (wave >> 1) << 6, wn = (wave & 1) << 6;
  const int col = lane & 15, quad = lane >> 4;
  float bb[4]; int nn[4];
  #pragma unroll
  for (int j = 0; j < 4; j++) { nn[j] = n0 + wn + 16*j + col; bb[j] = bias[nn[j]]; }

  if (mode < 2) {
    __bf16* dst = (mode == 0) ? qh : kh;
    #pragma unroll
    for (int i = 0; i < 4; i++)
      #pragma unroll
      for (int r = 0; r < 4; r++) {
        int m = m0 + wm + 16*i + quad*4 + r;
        int batch = m >> 11, s = m & (S_-1);
        #pragma unroll
        for (int j = 0; j < 4; j++) {
          int n = nn[j];
          dst[(((size_t)batch*H_ + (n >> 6))*S_ + s)*DH_ + (n & 63)] =
              (__bf16)(acc[i][j][r] + bb[j]);
        }
      }
  } else {
    // V: transposed store -> vt[b][h][d][s], pack 4 consecutive s per lane
    #pragma unroll
    for (int i = 0; i < 4; i++) {
      int mbase = m0 + wm + 16*i + quad*4;
      int batch = mbase >> 11, s0 = mbase & (S_-1);
      #pragma unroll
      for (int j = 0; j < 4; j++) {
        int n = nn[j];
        v4bf pk;
        #pragma unroll
        for (int r = 0; r < 4; r++) pk[r] = (__bf16)(acc[i][j][r] + bb[j]);
        *(v4bf*)(vt + (((size_t)batch*H_ + (n >> 6))*DH_ + (n & 63))*S_ + s0) = pk;
      }
    }
  }
}

// ---------------- flash attention: 64 queries/block, split-K across 4 waves ----------------
__global__ __launch_bounds__(256) void attn_kernel(
    const __bf16* __restrict__ qh, const __bf16* __restrict__ kh, const __bf16* __restrict__ vt,
    const float* __restrict__ mask, __bf16* __restrict__ ao)
{
  __shared__ __bf16 plds[4][4][16][40];  // [wave][qq][q within group][32 keys padded]
  __shared__ float mls[2][4][64];        // [m/l][wave][query]
  __shared__ float Ored[64][68];         // [query][d] fp32 combine buffer

  const int bh = blockIdx.y;
  const int wave = threadIdx.x >> 6, lane = threadIdx.x & 63;
  const int col = lane & 15, quad = lane >> 4, koff = quad << 3;
  const int q0 = blockIdx.x << 6;
  const int batch = bh / H_, h = bh % H_;
  const __bf16* qb = qh + (size_t)bh * S_ * DH_;
  const __bf16* kb = kh + (size_t)bh * S_ * DH_;
  const __bf16* vb = vt + (size_t)bh * DH_ * S_;
  __bf16 (*pt)[16][40] = plds[wave];

  v8bf Qf[4][2];
  #pragma unroll
  for (int qq = 0; qq < 4; qq++) {
    const __bf16* qr = qb + (size_t)(q0 + 16*qq + col)*DH_;
    Qf[qq][0] = *(const v8bf*)(qr + koff);
    Qf[qq][1] = *(const v8bf*)(qr + 32 + koff);
  }

  v4f O[4][4];
  #pragma unroll
  for (int f = 0; f < 4; f++)
    #pragma unroll
    for (int qq = 0; qq < 4; qq++) { v4f z = {0.f,0.f,0.f,0.f}; O[f][qq] = z; }
  float mi[4], li[4];
  #pragma unroll
  for (int qq = 0; qq < 4; qq++) { mi[qq] = -3e38f; li[qq] = 0.f; }
  const float C1 = 0.18033688011112042f;  // log2(e)/sqrt(DH)

  const int kbeg = wave << 9;
  #pragma unroll 1
  for (int kt = kbeg; kt < kbeg + 512; kt += 32) {
    const __bf16* kr0 = kb + (size_t)(kt + col)*DH_;
    const __bf16* kr1 = kb + (size_t)(kt + 16 + col)*DH_;
    v8bf Kf00 = *(const v8bf*)(kr0 + koff);
    v8bf Kf01 = *(const v8bf*)(kr0 + 32 + koff);
    v8bf Kf10 = *(const v8bf*)(kr1 + koff);
    v8bf Kf11 = *(const v8bf*)(kr1 + 32 + koff);

    #pragma unroll
    for (int qq = 0; qq < 4; qq++) {
      const float* mrow = mask + (size_t)(q0 + 16*qq + col)*S_ + kt + quad*4;
      float4 mk0 = *(const float4*)(mrow);
      float4 mk1 = *(const float4*)(mrow + 16);
      v4f s0 = {mk0.x, mk0.y, mk0.z, mk0.w};
      v4f s1 = {mk1.x, mk1.y, mk1.z, mk1.w};
      s0 = mfma16(Kf00, Qf[qq][0], s0); s0 = mfma16(Kf01, Qf[qq][1], s0);
      s1 = mfma16(Kf10, Qf[qq][0], s1); s1 = mfma16(Kf11, Qf[qq][1], s1);

      float x[8];
      #pragma unroll
      for (int j = 0; j < 4; j++) { x[j] = s0[j]*C1; x[4+j] = s1[j]*C1; }
      float xm = fmaxf(fmaxf(fmaxf(x[0],x[1]),fmaxf(x[2],x[3])),
                       fmaxf(fmaxf(x[4],x[5]),fmaxf(x[6],x[7])));
      xm = fmaxf(xm, __shfl_xor(xm, 16));
      xm = fmaxf(xm, __shfl_xor(xm, 32));
      float mold = mi[qq];
      float mn = fmaxf(mold, xm);
      mi[qq] = mn;
      float p[8], rs = 0.f;
      #pragma unroll
      for (int j = 0; j < 8; j++) { p[j] = exp2f(x[j] - mn); rs += p[j]; }
      rs += __shfl_xor(rs, 16);
      rs += __shfl_xor(rs, 32);
      if (__any(xm > mold)) {
        float alpha = exp2f(mold - mn);
        li[qq] = li[qq]*alpha + rs;
        #pragma unroll
        for (int f = 0; f < 4; f++) O[f][qq] *= alpha;
      } else {
        li[qq] += rs;
      }
      v4bf pk0, pk1;
      #pragma unroll
      for (int r = 0; r < 4; r++) { pk0[r] = (__bf16)p[r]; pk1[r] = (__bf16)p[4+r]; }
      *(v4bf*)(&pt[qq][col][quad*4])      = pk0;
      *(v4bf*)(&pt[qq][col][16 + quad*4]) = pk1;
    }

    v8bf Pf[4];
    #pragma unroll
    for (int qq = 0; qq < 4; qq++) Pf[qq] = *(const v8bf*)(&pt[qq][col][koff]);
    #pragma unroll
    for (int f = 0; f < 4; f++) {
      v8bf Vf = *(const v8bf*)(vb + (size_t)(f*16 + col)*S_ + kt + koff);
      #pragma unroll
      for (int qq = 0; qq < 4; qq++)
        O[f][qq] = mfma16(Vf, Pf[qq], O[f][qq]);
    }
  }

  // ---- in-block split-K combine ----
  if (quad == 0) {
    #pragma unroll
    for (int qq = 0; qq < 4; qq++) {
      mls[0][wave][16*qq + col] = mi[qq];
      mls[1][wave][16*qq + col] = li[qq];
    }
  }
  __syncthreads();
  float wgt[4];
  #pragma unroll
  for (int qq = 0; qq < 4; qq++) {
    int q = 16*qq + col;
    float ms = fmaxf(fmaxf(mls[0][0][q], mls[0][1][q]),
                     fmaxf(mls[0][2][q], mls[0][3][q]));
    wgt[qq] = exp2f(mi[qq] - ms);
  }
  for (int w = 0; w < 4; w++) {
    if (wave == w) {
      #pragma unroll
      for (int qq = 0; qq < 4; qq++)
        #pragma unroll
        for (int f = 0; f < 4; f++) {
          float4* dst = (float4*)&Ored[16*qq + col][16*f + quad*4];
          float4 val;
          val.x = O[f][qq][0]*wgt[qq]; val.y = O[f][qq][1]*wgt[qq];
          val.z = O[f][qq][2]*wgt[qq]; val.w = O[f][qq][3]*wgt[qq];
          if (w != 0) {
            float4 old = *dst;
            val.x += old.x; val.y += old.y; val.z += old.z; val.w += old.w;
          }
          *dst = val;
        }
    }
    __syncthreads();
  }
  {
    int q = threadIdx.x >> 2, ds = (threadIdx.x & 3) << 4;
    float msq = fmaxf(fmaxf(mls[0][0][q], mls[0][1][q]),
                      fmaxf(mls[0][2][q], mls[0][3][q]));
    float lst = 0.f;
    #pragma unroll
    for (int w = 0; w < 4; w++) lst += mls[1][w][q] * exp2f(mls[0][w][q] - msq);
    float invl = 1.f / lst;
    __bf16* orow = ao + ((size_t)batch*S_ + q0 + q)*D_ + h*DH_ + ds;
    v8bf o0, o1;
    #pragma unroll
    for (int i = 0; i < 8; i++) {
      o0[i] = (__bf16)(Ored[q][ds + i] * invl);
      o1[i] = (__bf16)(Ored[q][ds + 8 + i] * invl);
    }
    *(v8bf*)orow = o0;
    *(v8bf*)(orow + 8) = o1;
  }
}

// ---------------- output projection: fp32 out ----------------
__global__ __launch_bounds__(256) void out_gemm(
    const __bf16* __restrict__ Ao, const __bf16* __restrict__ Wob,
    const float* __restrict__ bo, float* __restrict__ out)
{
  __shared__ __bf16 lA[4096], lB[4096];
  const int m0 = blockIdx.y << 7, n0 = blockIdx.x << 7;
  v4f acc[4][4];
  #pragma unroll
  for (int i = 0; i < 4; i++)
    #pragma unroll
    for (int j = 0; j < 4; j++) { v4f z = {0.f,0.f,0.f,0.f}; acc[i][j] = z; }
  gemm_core_lds(Ao, Wob, m0, n0, lA, lB, acc);

  const int lane = threadIdx.x & 63;
  const int wave = threadIdx.x >> 6;
  const int wm = (wave >> 1) << 6, wn = (wave & 1) << 6;
  const int col = lane & 15, quad = lane >> 4;
  float bb[4]; int nn[4];
  #pragma unroll
  for (int j = 0; j < 4; j++) { nn[j] = n0 + wn + 16*j + col; bb[j] = bo[nn[j]]; }
  #pragma unroll
  for (int i = 0; i < 4; i++)
    #pragma unroll
    for (int r = 0; r < 4; r++) {
      int m = m0 + wm + 16*i + quad*4 + r;
      #pragma unroll
      for (int j = 0; j < 4; j++)
        out[(size_t)m*D_ + nn[j]] = acc[i][j][r] + bb[j];
    }
}

extern "C" void kernel_launch(void* const* d_in, const int* in_sizes, int n_in,
                              void* d_out, int out_size, void* d_ws, size_t ws_size,
                              hipStream_t stream)
{
  const float* q    = (const float*)d_in[0];
  const float* k    = (const float*)d_in[1];
  const float* v    = (const float*)d_in[2];
  const float* mask = (const float*)d_in[3];
  const float* Wq   = (const float*)d_in[4];
  const float* bq   = (const float*)d_in[5];
  const float* Wk   = (const float*)d_in[6];
  const float* bk   = (const float*)d_in[7];
  const float* Wv   = (const float*)d_in[8];
  const float* bv   = (const float*)d_in[9];
  const float* Wo   = (const float*)d_in[10];
  const float* bo   = (const float*)d_in[11];

  const size_t XN = (size_t)M_ * D_;
  const size_t WN = (size_t)D_ * D_;
  const size_t HN = (size_t)BH_ * S_ * DH_;

  char* ws = (char*)d_ws;
  __bf16* Xq  = (__bf16*)ws;                 ws += XN * 2;
  __bf16* Xk  = (__bf16*)ws;                 ws += XN * 2;
  __bf16* Xv  = (__bf16*)ws;                 ws += XN * 2;
  __bf16* Wqb = (__bf16*)ws;                 ws += WN * 2;
  __bf16* Wkb = (__bf16*)ws;                 ws += WN * 2;
  __bf16* Wvb = (__bf16*)ws;                 ws += WN * 2;
  __bf16* Wob = (__bf16*)ws;                 ws += WN * 2;
  __bf16* qhb = (__bf16*)ws;                 ws += HN * 2;
  __bf16* khb = (__bf16*)ws;                 ws += HN * 2;
  __bf16* vtb = (__bf16*)ws;                 ws += HN * 2;
  __bf16* aob = (__bf16*)ws;                 ws += XN * 2;

  convert_kernel<<<dim3(3072, 7), 256, 0, stream>>>(
      q, k, v, Wq, Wk, Wv, Wo, Xq, Xk, Xv, Wqb, Wkb, Wvb, Wob);
  qkv_gemm<<<dim3(6, 32, 3), 256, 0, stream>>>(
      Xq, Xk, Xv, Wqb, Wkb, Wvb, bq, bk, bv, qhb, khb, vtb);
  attn_kernel<<<dim3(32, 24), 256, 0, stream>>>(qhb, khb, vtb, mask, aob);
  out_gemm<<<dim3(6, 32), 256, 0, stream>>>(aob, Wob, bo, (float*)d_out);
}